// Round 13
// baseline (147.658 us; speedup 1.0000x reference)
//
#include <hip/hip_runtime.h>

typedef __attribute__((ext_vector_type(4))) float f32x4;
typedef __attribute__((ext_vector_type(8))) short bf16x8;

#define EPS2 1e-16f
constexpr int PBLOCK = 256;
constexpr int BLOCK  = 256;   // 4 waves; each wave = 2 x 64-source tiles
constexpr float LOG2E = 1.4426950408889634f;

__device__ __forceinline__ float rcpf_fast(float x){ return __builtin_amdgcn_rcpf(x); }
__device__ __forceinline__ float rsqf_fast(float x){ return __builtin_amdgcn_rsqf(x); }
__device__ __forceinline__ float exp2_fast(float x){ return __builtin_amdgcn_exp2f(x); }
__device__ __forceinline__ unsigned cvt_pk_bf16(float lo, float hi){
    unsigned d;
    asm("v_cvt_pk_bf16_f32 %0, %1, %2" : "=v"(d) : "v"(lo), "v"(hi));
    return d;
}
__device__ __forceinline__ bf16x8 as_frag(int4 v){
    union { int4 i; bf16x8 f; } u; u.i = v; return u.f;
}

// ws layout (floats):
//   [0,256)      W1u: u32[m=64][4]   A1 operand (folded W1 col m + bias), K=8 real
//   [256,384)    W2u: u32[j=4][32]   A2 operand, h-PERMUTED so GEMM1's C register
//                layout IS GEMM2's B fragment:
//                word [j][kt*16+q*4+w] = bf16pair(-2*W2[m],-2*W2[m+1]),
//                m = 32*kt + (w>>1)*16 + 4*q + (w&1)*2
//                Kernel reads row j' of A2 as W2u[j' & 3] (row duplication):
//                C row q*4+r then holds o[r] for ALL q -> no o-gather shuffles.
//   [384,384+4S) sPA float4: {px*invL, py*invL, pz*invL, area}
//   [+4S,+8S)    sNB float4: {nhx, nhy, nhz, log2(n2)}
//   [+8S,+9S)    sw : strengths
//
// Algebra (exact, rounds 5-12): a_reg = -log2e*a_true; hv_reg = a_reg*sigmoid(a_true);
// W2'' = -2*W2 -> o_reg = 2*log2e*o_true; tanh(o_true) = (E-1)/(E+1), E = exp2(o_reg).
__global__ void prep(const float* __restrict__ refLenP,
                     const float* __restrict__ srcP,
                     const float* __restrict__ srcN,
                     const float* __restrict__ wgtP,
                     const float* __restrict__ areaP,
                     const float* __restrict__ W1,
                     const float* __restrict__ b1,
                     const float* __restrict__ W2,
                     float* __restrict__ ws,
                     float* __restrict__ outZ, int outN, int S)
{
    const int nSrcBlk = (S + PBLOCK - 1) / PBLOCK;
    const int bid = blockIdx.x;
    if (bid < nSrcBlk) {
        const int s = bid * PBLOCK + threadIdx.x;
        if (s < S) {
            const float invL = rcpf_fast(refLenP[0]);
            float px = srcP[s*3+0]*invL, py = srcP[s*3+1]*invL, pz = srcP[s*3+2]*invL;
            float nx = srcN[s*3+0], ny = srcN[s*3+1], nz = srcN[s*3+2];
            float n2 = fmaf(nx,nx, fmaf(ny,ny, nz*nz)) + EPS2;
            float inv_n = rsqf_fast(n2);
            float l2n = __log2f(n2);
            float4* sPA = (float4*)(ws + 384);
            float4* sNB = (float4*)(ws + 384 + 4*S);
            float*  sw  = ws + 384 + 8*S;
            sPA[s] = make_float4(px, py, pz, areaP[s]);
            sNB[s] = make_float4(nx*inv_n, ny*inv_n, nz*inv_n, l2n);
            sw[s]  = wgtP[s];
        }
    } else if (bid == nSrcBlk) {
        const int t = threadIdx.x;
        unsigned* W1u = (unsigned*)ws;
        unsigned* W2u = (unsigned*)ws + 256;
        if (t < 64) {
            const int h = t;              // h == GEMM1 M-index (identity)
            float v[8];
            v[0] = -LOG2E * W1[0*64 + h];   // area
            v[1] = -0.5f  * W1[1*64 + h];   // * log2(r2)
            v[2] = -0.5f  * W1[2*64 + h];   // * log2(n2)
            v[3] = -LOG2E * W1[3*64 + h];   // P1
            v[4] = -LOG2E * W1[4*64 + h];   // P2
            v[5] = -LOG2E * W1[5*64 + h];   // P3
            v[6] = -LOG2E * W1[6*64 + h];   // P4
            v[7] = -LOG2E * b1[h];          // bias (feature 7 == 1.0)
            #pragma unroll
            for (int r = 0; r < 4; ++r)
                W1u[h*4 + r] = cvt_pk_bf16(v[2*r], v[2*r+1]);
        } else if (t < 192) {
            const int idx = t - 64;        // 128 threads: [j=4][u=32]
            const int j = idx >> 5;
            const int u = idx & 31;
            const int kt = u >> 4;
            const int q  = (u >> 2) & 3;
            const int w  = u & 3;
            const int m = 32*kt + (w>>1)*16 + 4*q + (w&1)*2;
            float a = -2.0f * W2[ m      * 4 + j];
            float b = -2.0f * W2[(m + 1) * 4 + j];
            W2u[j*32 + u] = cvt_pk_bf16(a, b);
        }
    } else {
        // zero the output for atomic accumulation
        const int i = (bid - nSrcBlk - 1) * PBLOCK + threadIdx.x;
        if (i < outN) outZ[i] = 0.0f;
    }
}

__global__ __launch_bounds__(BLOCK, 8)
void bh_kernel(const float* __restrict__ refLenP,
               const float* __restrict__ tgtP,
               const float* __restrict__ b2,
               const float* __restrict__ ws,
               float* __restrict__ out,
               int S, int T)
{
    __shared__ float red[4][4];

    const int tid = threadIdx.x;
    const int wv  = tid >> 6;
    const int l   = tid & 63;
    const int col = l & 15;
    const int q   = l >> 4;
    const int bid = blockIdx.x;
    const int t     = bid >> 1;   // target
    const int chunk = bid & 1;    // source half (512 each)

    const unsigned* __restrict__ W1u = (const unsigned*)ws;
    const unsigned* __restrict__ W2u = (const unsigned*)ws + 256;
    const float4* __restrict__ sPA = (const float4*)(ws + 384);
    const float4* __restrict__ sNB = (const float4*)(ws + 384 + 4*S);
    const float*  __restrict__ sw  = ws + 384 + 8*S;

    // A1: W1' [64m x 8k] (K=32; real k 0..7 live in q==0 lanes)
    int4 A1[4];
    #pragma unroll
    for (int mt = 0; mt < 4; ++mt) {
        int4 r = *(const int4*)&W1u[(mt*16 + col) * 4];
        A1[mt] = (q == 0) ? r : make_int4(0,0,0,0);
    }
    // A2: row j' reads W2 row (j' & 3)  -> ALL rows real (duplicated x4).
    // C row q*4+r then equals o[r] for every q: epilogue needs NO shuffles.
    int4 A2[2];
    #pragma unroll
    for (int kt = 0; kt < 2; ++kt) {
        const int src = col & 3;
        A2[kt] = *(const int4*)&W2u[src*32 + kt*16 + q*4];
    }

    const float invL = rcpf_fast(refLenP[0]);
    const float tx = tgtP[t*3+0]*invL;
    const float ty = tgtP[t*3+1]*invL;
    const float tz = tgtP[t*3+2]*invL;
    const float s2 = 2.0f * LOG2E;
    const f32x4 b2init = { s2*b2[0], s2*b2[1], s2*b2[2], s2*b2[3] };
    const f32x4 zero4  = { 0.f, 0.f, 0.f, 0.f };

    float acc0 = 0.f, acc1 = 0.f, acc2 = 0.f, acc3 = 0.f;

    for (int it = 0; it < 2; ++it) {
        const int s  = chunk*512 + it*256 + wv*64 + l;
        const int sc = (s < S) ? s : 0;
        const float4 pa = sPA[sc];
        const float4 nb = sNB[sc];
        const float wgt = (s < S) ? sw[sc] : 0.f;

        // features (registers)
        float rx = tx - pa.x, ry = ty - pa.y, rz = tz - pa.z;
        float r2 = fmaf(rx,rx, fmaf(ry,ry, fmaf(rz,rz, EPS2)));
        float ir = rsqf_fast(r2);
        float l2r = __log2f(r2);
        float cosv = fmaf(rx,nb.x, fmaf(ry,nb.y, rz*nb.z)) * ir;
        float c2 = cosv * cosv;
        float P2 = fmaf(c2, 1.5f, -0.5f);
        float P3 = (c2*2.5f - 1.5f) * cosv;
        float P4 = fmaf(fmaf(c2, 4.375f, -3.75f), c2, 0.375f);
        unsigned fp0 = cvt_pk_bf16(pa.w, l2r);
        unsigned fp1 = cvt_pk_bf16(nb.w, cosv);
        unsigned fp2 = cvt_pk_bf16(P2,   P3);
        unsigned fp3 = cvt_pk_bf16(P4,   1.0f);

        // B1 gathers (16 bpermute, hoisted together)
        int4 b1i[4];
        #pragma unroll
        for (int pb = 0; pb < 4; ++pb) {
            const int srcl = pb*16 + col;
            b1i[pb] = make_int4((int)__shfl(fp0, srcl), (int)__shfl(fp1, srcl),
                                (int)__shfl(fp2, srcl), (int)__shfl(fp3, srcl));
        }

        f32x4 ov = zero4;
        #pragma unroll
        for (int pb = 0; pb < 4; ++pb) {
            bf16x8 B1 = as_frag(b1i[pb]);
            unsigned pk[4][2];
            #pragma unroll
            for (int mt = 0; mt < 4; ++mt) {
                f32x4 c1 = __builtin_amdgcn_mfma_f32_16x16x32_bf16(
                               as_frag(A1[mt]), B1, zero4, 0, 0, 0);
                float hv0, hv1, hv2, hv3;
                { float e = exp2_fast(c1[0]); hv0 = c1[0] * rcpf_fast(1.0f + e); }
                { float e = exp2_fast(c1[1]); hv1 = c1[1] * rcpf_fast(1.0f + e); }
                { float e = exp2_fast(c1[2]); hv2 = c1[2] * rcpf_fast(1.0f + e); }
                { float e = exp2_fast(c1[3]); hv3 = c1[3] * rcpf_fast(1.0f + e); }
                pk[mt][0] = cvt_pk_bf16(hv0, hv1);
                pk[mt][1] = cvt_pk_bf16(hv2, hv3);
            }
            int4 B2a = make_int4((int)pk[0][0], (int)pk[0][1], (int)pk[1][0], (int)pk[1][1]);
            int4 B2b = make_int4((int)pk[2][0], (int)pk[2][1], (int)pk[3][0], (int)pk[3][1]);
            f32x4 oa = b2init;
            oa = __builtin_amdgcn_mfma_f32_16x16x32_bf16(as_frag(A2[0]), as_frag(B2a), oa, 0, 0, 0);
            oa = __builtin_amdgcn_mfma_f32_16x16x32_bf16(as_frag(A2[1]), as_frag(B2b), oa, 0, 0, 0);
            // my pair (q*16+col) lives in block pb==q, regs 0..3 = o[0..3]
            #pragma unroll
            for (int k = 0; k < 4; ++k)
                ov[k] = (q == pb) ? oa[k] : ov[k];
        }

        // epilogue: tanh, cross, weighted accumulation
        float tt[4];
        #pragma unroll
        for (int k = 0; k < 4; ++k) {
            float m = __builtin_amdgcn_fmed3f(ov[k], -126.f, 126.f);
            float E = exp2_fast(m);
            tt[k] = (E - 1.0f) * rcpf_fast(E + 1.0f);
        }
        float wsv = wgt * ir;        // w * inv_r
        float wvv = wsv * ir;        // w * inv_r^2
        acc0 = fmaf(wsv, tt[0], acc0);
        float rhx = rx*ir, rhy = ry*ir, rhz = rz*ir;
        float cxx = rhy*nb.z - rhz*nb.y;
        float cxy = rhz*nb.x - rhx*nb.z;
        float cxz = rhx*nb.y - rhy*nb.x;
        float vx = tt[1]*rhx + tt[2]*nb.x + tt[3]*cxx;
        float vy = tt[1]*rhy + tt[2]*nb.y + tt[3]*cxy;
        float vz = tt[1]*rhz + tt[2]*nb.z + tt[3]*cxz;
        acc1 = fmaf(wvv, vx, acc1);
        acc2 = fmaf(wvv, vy, acc2);
        acc3 = fmaf(wvv, vz, acc3);
    }

    // ---- block reduction + atomic combine across the 2 chunk-blocks ----
    #pragma unroll
    for (int off = 32; off > 0; off >>= 1) {
        acc0 += __shfl_down(acc0, off);
        acc1 += __shfl_down(acc1, off);
        acc2 += __shfl_down(acc2, off);
        acc3 += __shfl_down(acc3, off);
    }
    if (l == 0) {
        red[wv][0] = acc0; red[wv][1] = acc1;
        red[wv][2] = acc2; red[wv][3] = acc3;
    }
    __syncthreads();
    if (tid < 4) {
        float v = red[0][tid] + red[1][tid] + red[2][tid] + red[3][tid];
        atomicAdd(&out[t*4 + tid], v);
    }
}

extern "C" void kernel_launch(void* const* d_in, const int* in_sizes, int n_in,
                              void* d_out, int out_size, void* d_ws, size_t ws_size,
                              hipStream_t stream) {
    const float* refLen = (const float*)d_in[0];
    const float* srcP   = (const float*)d_in[1];
    const float* tgtP   = (const float*)d_in[2];
    const float* w      = (const float*)d_in[3];
    const float* area   = (const float*)d_in[4];
    const float* srcN   = (const float*)d_in[5];
    const float* W1     = (const float*)d_in[6];
    const float* b1     = (const float*)d_in[7];
    const float* W2     = (const float*)d_in[8];
    const float* b2     = (const float*)d_in[9];
    float* out          = (float*)d_out;
    float* ws           = (float*)d_ws;

    const int S = in_sizes[3];
    const int T = in_sizes[2] / 3;
    const int nSrcBlk = (S + PBLOCK - 1) / PBLOCK;
    const int nZeroBlk = (out_size + PBLOCK - 1) / PBLOCK;

    prep<<<nSrcBlk + 1 + nZeroBlk, PBLOCK, 0, stream>>>(
        refLen, srcP, srcN, w, area, W1, b1, W2, ws, out, out_size, S);
    bh_kernel<<<T * 2, BLOCK, 0, stream>>>(refLen, tgtP, b2, ws, out, S, T);
}

// Round 14
// 106.851 us; speedup vs baseline: 1.3819x; 1.3819x over previous
//
#include <hip/hip_runtime.h>

typedef __attribute__((ext_vector_type(4))) float f32x4;
typedef __attribute__((ext_vector_type(8))) short bf16x8;

#define EPS2 1e-16f
constexpr int PBLOCK = 256;
constexpr int BLOCK  = 256;   // 4 waves; each wave = 2 x 64-source tiles
constexpr float LOG2E = 1.4426950408889634f;

__device__ __forceinline__ float rcpf_fast(float x){ return __builtin_amdgcn_rcpf(x); }
__device__ __forceinline__ float rsqf_fast(float x){ return __builtin_amdgcn_rsqf(x); }
__device__ __forceinline__ float exp2_fast(float x){ return __builtin_amdgcn_exp2f(x); }
__device__ __forceinline__ unsigned cvt_pk_bf16(float lo, float hi){
    unsigned d;
    asm("v_cvt_pk_bf16_f32 %0, %1, %2" : "=v"(d) : "v"(lo), "v"(hi));
    return d;
}
__device__ __forceinline__ bf16x8 as_frag(int4 v){
    union { int4 i; bf16x8 f; } u; u.i = v; return u.f;
}

// ws layout (floats):
//   [0,256)      W1u: u32[m=64][4]   A1 operand (folded W1 col m + bias), K=8 real
//   [256,384)    W2u: u32[j=4][32]   A2 operand, h-PERMUTED so GEMM1's C register
//                layout IS GEMM2's B fragment:
//                word [j][kt*16+q*4+w] = bf16pair(-2*W2[m],-2*W2[m+1]),
//                m = 32*kt + (w>>1)*16 + 4*q + (w&1)*2
//                Kernel reads row j' of A2 as W2u[j' & 3] (row duplication):
//                C row q*4+r then holds o[r] for ALL q -> no o-gather shuffles.
//   [384,384+4S) sPA float4: {px*invL, py*invL, pz*invL, area}
//   [+4S,+8S)    sNB float4: {nhx, nhy, nhz, log2(n2)}
//   [+8S,+9S)    sw : strengths
//
// Algebra (exact, rounds 5-13): a_reg = -log2e*a_true; hv_reg = a_reg*sigmoid(a_true);
// W2'' = -2*W2 -> o_reg = 2*log2e*o_true; tanh(o_true) = (E-1)/(E+1), E = exp2(o_reg).
//
// NOTE (r6, r13 lesson): never force waves/EU beyond natural register usage —
// launch_bounds(256,8) squeezed to 32 VGPR and spilled 327 MB/dispatch to scratch.
__global__ void prep(const float* __restrict__ refLenP,
                     const float* __restrict__ srcP,
                     const float* __restrict__ srcN,
                     const float* __restrict__ wgtP,
                     const float* __restrict__ areaP,
                     const float* __restrict__ W1,
                     const float* __restrict__ b1,
                     const float* __restrict__ W2,
                     float* __restrict__ ws,
                     float* __restrict__ outZ, int outN, int S)
{
    const int nSrcBlk = (S + PBLOCK - 1) / PBLOCK;
    const int bid = blockIdx.x;
    if (bid < nSrcBlk) {
        const int s = bid * PBLOCK + threadIdx.x;
        if (s < S) {
            const float invL = rcpf_fast(refLenP[0]);
            float px = srcP[s*3+0]*invL, py = srcP[s*3+1]*invL, pz = srcP[s*3+2]*invL;
            float nx = srcN[s*3+0], ny = srcN[s*3+1], nz = srcN[s*3+2];
            float n2 = fmaf(nx,nx, fmaf(ny,ny, nz*nz)) + EPS2;
            float inv_n = rsqf_fast(n2);
            float l2n = __log2f(n2);
            float4* sPA = (float4*)(ws + 384);
            float4* sNB = (float4*)(ws + 384 + 4*S);
            float*  sw  = ws + 384 + 8*S;
            sPA[s] = make_float4(px, py, pz, areaP[s]);
            sNB[s] = make_float4(nx*inv_n, ny*inv_n, nz*inv_n, l2n);
            sw[s]  = wgtP[s];
        }
    } else if (bid == nSrcBlk) {
        const int t = threadIdx.x;
        unsigned* W1u = (unsigned*)ws;
        unsigned* W2u = (unsigned*)ws + 256;
        if (t < 64) {
            const int h = t;              // h == GEMM1 M-index (identity)
            float v[8];
            v[0] = -LOG2E * W1[0*64 + h];   // area
            v[1] = -0.5f  * W1[1*64 + h];   // * log2(r2)
            v[2] = -0.5f  * W1[2*64 + h];   // * log2(n2)
            v[3] = -LOG2E * W1[3*64 + h];   // P1
            v[4] = -LOG2E * W1[4*64 + h];   // P2
            v[5] = -LOG2E * W1[5*64 + h];   // P3
            v[6] = -LOG2E * W1[6*64 + h];   // P4
            v[7] = -LOG2E * b1[h];          // bias (feature 7 == 1.0)
            #pragma unroll
            for (int r = 0; r < 4; ++r)
                W1u[h*4 + r] = cvt_pk_bf16(v[2*r], v[2*r+1]);
        } else if (t < 192) {
            const int idx = t - 64;        // 128 threads: [j=4][u=32]
            const int j = idx >> 5;
            const int u = idx & 31;
            const int kt = u >> 4;
            const int q  = (u >> 2) & 3;
            const int w  = u & 3;
            const int m = 32*kt + (w>>1)*16 + 4*q + (w&1)*2;
            float a = -2.0f * W2[ m      * 4 + j];
            float b = -2.0f * W2[(m + 1) * 4 + j];
            W2u[j*32 + u] = cvt_pk_bf16(a, b);
        }
    } else {
        // zero the output for atomic accumulation
        const int i = (bid - nSrcBlk - 1) * PBLOCK + threadIdx.x;
        if (i < outN) outZ[i] = 0.0f;
    }
}

__global__ __launch_bounds__(BLOCK, 4)
void bh_kernel(const float* __restrict__ refLenP,
               const float* __restrict__ tgtP,
               const float* __restrict__ b2,
               const float* __restrict__ ws,
               float* __restrict__ out,
               int S, int T)
{
    __shared__ float red[4][4];

    const int tid = threadIdx.x;
    const int wv  = tid >> 6;
    const int l   = tid & 63;
    const int col = l & 15;
    const int q   = l >> 4;
    const int bid = blockIdx.x;
    const int t     = bid >> 1;   // target
    const int chunk = bid & 1;    // source half (512 each)

    const unsigned* __restrict__ W1u = (const unsigned*)ws;
    const unsigned* __restrict__ W2u = (const unsigned*)ws + 256;
    const float4* __restrict__ sPA = (const float4*)(ws + 384);
    const float4* __restrict__ sNB = (const float4*)(ws + 384 + 4*S);
    const float*  __restrict__ sw  = ws + 384 + 8*S;

    // A1: W1' [64m x 8k] (K=32; real k 0..7 live in q==0 lanes)
    int4 A1[4];
    #pragma unroll
    for (int mt = 0; mt < 4; ++mt) {
        int4 r = *(const int4*)&W1u[(mt*16 + col) * 4];
        A1[mt] = (q == 0) ? r : make_int4(0,0,0,0);
    }
    // A2: row j' reads W2 row (j' & 3)  -> ALL rows real (duplicated x4).
    // C row q*4+r then equals o[r] for every q: epilogue needs NO shuffles.
    int4 A2[2];
    #pragma unroll
    for (int kt = 0; kt < 2; ++kt) {
        const int src = col & 3;
        A2[kt] = *(const int4*)&W2u[src*32 + kt*16 + q*4];
    }

    const float invL = rcpf_fast(refLenP[0]);
    const float tx = tgtP[t*3+0]*invL;
    const float ty = tgtP[t*3+1]*invL;
    const float tz = tgtP[t*3+2]*invL;
    const float s2 = 2.0f * LOG2E;
    const f32x4 b2init = { s2*b2[0], s2*b2[1], s2*b2[2], s2*b2[3] };
    const f32x4 zero4  = { 0.f, 0.f, 0.f, 0.f };

    float acc0 = 0.f, acc1 = 0.f, acc2 = 0.f, acc3 = 0.f;

    for (int it = 0; it < 2; ++it) {
        const int s  = chunk*512 + it*256 + wv*64 + l;
        const int sc = (s < S) ? s : 0;
        const float4 pa = sPA[sc];
        const float4 nb = sNB[sc];
        const float wgt = (s < S) ? sw[sc] : 0.f;

        // features (registers)
        float rx = tx - pa.x, ry = ty - pa.y, rz = tz - pa.z;
        float r2 = fmaf(rx,rx, fmaf(ry,ry, fmaf(rz,rz, EPS2)));
        float ir = rsqf_fast(r2);
        float l2r = __log2f(r2);
        float cosv = fmaf(rx,nb.x, fmaf(ry,nb.y, rz*nb.z)) * ir;
        float c2 = cosv * cosv;
        float P2 = fmaf(c2, 1.5f, -0.5f);
        float P3 = (c2*2.5f - 1.5f) * cosv;
        float P4 = fmaf(fmaf(c2, 4.375f, -3.75f), c2, 0.375f);
        unsigned fp0 = cvt_pk_bf16(pa.w, l2r);
        unsigned fp1 = cvt_pk_bf16(nb.w, cosv);
        unsigned fp2 = cvt_pk_bf16(P2,   P3);
        unsigned fp3 = cvt_pk_bf16(P4,   1.0f);

        // B1 gathers (16 bpermute, hoisted together)
        int4 b1i[4];
        #pragma unroll
        for (int pb = 0; pb < 4; ++pb) {
            const int srcl = pb*16 + col;
            b1i[pb] = make_int4((int)__shfl(fp0, srcl), (int)__shfl(fp1, srcl),
                                (int)__shfl(fp2, srcl), (int)__shfl(fp3, srcl));
        }

        f32x4 ov = zero4;
        #pragma unroll
        for (int pb = 0; pb < 4; ++pb) {
            bf16x8 B1 = as_frag(b1i[pb]);
            unsigned pk[4][2];
            #pragma unroll
            for (int mt = 0; mt < 4; ++mt) {
                f32x4 c1 = __builtin_amdgcn_mfma_f32_16x16x32_bf16(
                               as_frag(A1[mt]), B1, zero4, 0, 0, 0);
                float hv0, hv1, hv2, hv3;
                { float e = exp2_fast(c1[0]); hv0 = c1[0] * rcpf_fast(1.0f + e); }
                { float e = exp2_fast(c1[1]); hv1 = c1[1] * rcpf_fast(1.0f + e); }
                { float e = exp2_fast(c1[2]); hv2 = c1[2] * rcpf_fast(1.0f + e); }
                { float e = exp2_fast(c1[3]); hv3 = c1[3] * rcpf_fast(1.0f + e); }
                pk[mt][0] = cvt_pk_bf16(hv0, hv1);
                pk[mt][1] = cvt_pk_bf16(hv2, hv3);
            }
            int4 B2a = make_int4((int)pk[0][0], (int)pk[0][1], (int)pk[1][0], (int)pk[1][1]);
            int4 B2b = make_int4((int)pk[2][0], (int)pk[2][1], (int)pk[3][0], (int)pk[3][1]);
            f32x4 oa = b2init;
            oa = __builtin_amdgcn_mfma_f32_16x16x32_bf16(as_frag(A2[0]), as_frag(B2a), oa, 0, 0, 0);
            oa = __builtin_amdgcn_mfma_f32_16x16x32_bf16(as_frag(A2[1]), as_frag(B2b), oa, 0, 0, 0);
            // my pair (q*16+col) lives in block pb==q, regs 0..3 = o[0..3]
            #pragma unroll
            for (int k = 0; k < 4; ++k)
                ov[k] = (q == pb) ? oa[k] : ov[k];
        }

        // epilogue: tanh, cross, weighted accumulation
        float tt[4];
        #pragma unroll
        for (int k = 0; k < 4; ++k) {
            float m = __builtin_amdgcn_fmed3f(ov[k], -126.f, 126.f);
            float E = exp2_fast(m);
            tt[k] = (E - 1.0f) * rcpf_fast(E + 1.0f);
        }
        float wsv = wgt * ir;        // w * inv_r
        float wvv = wsv * ir;        // w * inv_r^2
        acc0 = fmaf(wsv, tt[0], acc0);
        float rhx = rx*ir, rhy = ry*ir, rhz = rz*ir;
        float cxx = rhy*nb.z - rhz*nb.y;
        float cxy = rhz*nb.x - rhx*nb.z;
        float cxz = rhx*nb.y - rhy*nb.x;
        float vx = tt[1]*rhx + tt[2]*nb.x + tt[3]*cxx;
        float vy = tt[1]*rhy + tt[2]*nb.y + tt[3]*cxy;
        float vz = tt[1]*rhz + tt[2]*nb.z + tt[3]*cxz;
        acc1 = fmaf(wvv, vx, acc1);
        acc2 = fmaf(wvv, vy, acc2);
        acc3 = fmaf(wvv, vz, acc3);
    }

    // ---- block reduction + atomic combine across the 2 chunk-blocks ----
    #pragma unroll
    for (int off = 32; off > 0; off >>= 1) {
        acc0 += __shfl_down(acc0, off);
        acc1 += __shfl_down(acc1, off);
        acc2 += __shfl_down(acc2, off);
        acc3 += __shfl_down(acc3, off);
    }
    if (l == 0) {
        red[wv][0] = acc0; red[wv][1] = acc1;
        red[wv][2] = acc2; red[wv][3] = acc3;
    }
    __syncthreads();
    if (tid < 4) {
        float v = red[0][tid] + red[1][tid] + red[2][tid] + red[3][tid];
        atomicAdd(&out[t*4 + tid], v);
    }
}

extern "C" void kernel_launch(void* const* d_in, const int* in_sizes, int n_in,
                              void* d_out, int out_size, void* d_ws, size_t ws_size,
                              hipStream_t stream) {
    const float* refLen = (const float*)d_in[0];
    const float* srcP   = (const float*)d_in[1];
    const float* tgtP   = (const float*)d_in[2];
    const float* w      = (const float*)d_in[3];
    const float* area   = (const float*)d_in[4];
    const float* srcN   = (const float*)d_in[5];
    const float* W1     = (const float*)d_in[6];
    const float* b1     = (const float*)d_in[7];
    const float* W2     = (const float*)d_in[8];
    const float* b2     = (const float*)d_in[9];
    float* out          = (float*)d_out;
    float* ws           = (float*)d_ws;

    const int S = in_sizes[3];
    const int T = in_sizes[2] / 3;
    const int nSrcBlk = (S + PBLOCK - 1) / PBLOCK;
    const int nZeroBlk = (out_size + PBLOCK - 1) / PBLOCK;

    prep<<<nSrcBlk + 1 + nZeroBlk, PBLOCK, 0, stream>>>(
        refLen, srcP, srcN, w, area, W1, b1, W2, ws, out, out_size, S);
    bh_kernel<<<T * 2, BLOCK, 0, stream>>>(refLen, tgtP, b2, ws, out, S, T);
}